// Round 1
// baseline (6710.368 us; speedup 1.0000x reference)
//
#include <hip/hip_runtime.h>
#include <hip/hip_bf16.h>

#define R_TOTAL 12288   // 8 * 12 * 128 rows
#define NGROUP  96      // 8 * 12 (b,n) groups, 128 t-steps each
#define HID     8192
#define EPS     1e-5f

// ---------------------------------------------------------------------------
// Generic tiled fp32 GEMM with bias: C[M,N] = A[M,K] @ B[K,N] + bias[N]
// Requires: M % BM == 0, N % BN == 0, K % BK == 0, blockDim 256.
// ---------------------------------------------------------------------------
template <int BM, int BN, int BK, int TM, int TN>
__global__ __launch_bounds__(256) void gemm_bias(
    const float* __restrict__ A, const float* __restrict__ B,
    const float* __restrict__ bias, float* __restrict__ C,
    int M, int N, int K)
{
    __shared__ float As[BK][BM + 4];   // transposed: As[k][m]
    __shared__ float Bs[BK][BN + 4];   // Bs[k][n]

    const int tid  = threadIdx.x;
    const int ncol = BN / TN;          // threads along N
    const int tx   = tid % ncol;
    const int ty   = tid / ncol;
    const int m0   = blockIdx.y * BM;
    const int n0   = blockIdx.x * BN;

    float acc[TM][TN];
#pragma unroll
    for (int i = 0; i < TM; ++i)
#pragma unroll
        for (int j = 0; j < TN; ++j) acc[i][j] = 0.f;

    for (int k0 = 0; k0 < K; k0 += BK) {
        // ---- load A tile (BM x BK) -> As[k][m] (transposed) ----
#pragma unroll
        for (int i = 0; i < (BM * BK) / 1024; ++i) {
            int f4  = tid + i * 256;
            int row = f4 / (BK / 4);
            int kq  = f4 % (BK / 4);
            float4 v = *(const float4*)&A[(size_t)(m0 + row) * K + k0 + kq * 4];
            As[kq * 4 + 0][row] = v.x;
            As[kq * 4 + 1][row] = v.y;
            As[kq * 4 + 2][row] = v.z;
            As[kq * 4 + 3][row] = v.w;
        }
        // ---- load B tile (BK x BN) -> Bs[k][n] ----
#pragma unroll
        for (int i = 0; i < (BK * BN) / 1024; ++i) {
            int f4  = tid + i * 256;
            int row = f4 / (BN / 4);
            int cq  = f4 % (BN / 4);
            *(float4*)&Bs[row][cq * 4] =
                *(const float4*)&B[(size_t)(k0 + row) * N + n0 + cq * 4];
        }
        __syncthreads();

#pragma unroll
        for (int kk = 0; kk < BK; ++kk) {
            float a[TM], b[TN];
#pragma unroll
            for (int i = 0; i < TM / 4; ++i)
                *(float4*)&a[i * 4] = *(const float4*)&As[kk][ty * TM + i * 4];
#pragma unroll
            for (int j = 0; j < TN / 4; ++j)
                *(float4*)&b[j * 4] = *(const float4*)&Bs[kk][tx * TN + j * 4];
#pragma unroll
            for (int i = 0; i < TM; ++i)
#pragma unroll
                for (int j = 0; j < TN; ++j)
                    acc[i][j] = fmaf(a[i], b[j], acc[i][j]);
        }
        __syncthreads();
    }

    // ---- epilogue: bias + store ----
#pragma unroll
    for (int i = 0; i < TM; ++i) {
#pragma unroll
        for (int j = 0; j < TN / 4; ++j) {
            int n = n0 + tx * TN + j * 4;
            float4 o;
            o.x = acc[i][j * 4 + 0] + bias[n + 0];
            o.y = acc[i][j * 4 + 1] + bias[n + 1];
            o.z = acc[i][j * 4 + 2] + bias[n + 2];
            o.w = acc[i][j * 4 + 3] + bias[n + 3];
            *(float4*)&C[(size_t)(m0 + ty * TM + i) * N + n] = o;
        }
    }
}

// ---------------------------------------------------------------------------
// In-place LayerNorm (over HID) + affine + ReLU. One 256-thread block per row.
// Row (8192 floats) held in registers: 8 float4 per thread.
// ---------------------------------------------------------------------------
__global__ __launch_bounds__(256) void ln_relu(
    float* __restrict__ H, const float* __restrict__ gw,
    const float* __restrict__ bw)
{
    const int row = blockIdx.x;
    const int tid = threadIdx.x;
    float* h = H + (size_t)row * HID;

    float4 v[8];
    float sum = 0.f, ssq = 0.f;
#pragma unroll
    for (int i = 0; i < 8; ++i) {
        v[i] = *(const float4*)&h[(tid + i * 256) * 4];
        sum += v[i].x + v[i].y + v[i].z + v[i].w;
        ssq += v[i].x * v[i].x + v[i].y * v[i].y + v[i].z * v[i].z + v[i].w * v[i].w;
    }
    // wave (64) reduce then cross-wave via LDS
#pragma unroll
    for (int off = 32; off > 0; off >>= 1) {
        sum += __shfl_down(sum, off, 64);
        ssq += __shfl_down(ssq, off, 64);
    }
    __shared__ float s_sum[4], s_ssq[4];
    int wave = tid >> 6, lane = tid & 63;
    if (lane == 0) { s_sum[wave] = sum; s_ssq[wave] = ssq; }
    __syncthreads();
    float tot = s_sum[0] + s_sum[1] + s_sum[2] + s_sum[3];
    float tsq = s_ssq[0] + s_ssq[1] + s_ssq[2] + s_ssq[3];

    const float mu  = tot / (float)HID;
    float var = tsq / (float)HID - mu * mu;
    var = var < 0.f ? 0.f : var;
    const float rs  = rsqrtf(var + EPS);

#pragma unroll
    for (int i = 0; i < 8; ++i) {
        int c = (tid + i * 256) * 4;
        float4 g4 = *(const float4*)&gw[c];
        float4 b4 = *(const float4*)&bw[c];
        float4 o;
        o.x = (v[i].x - mu) * rs * g4.x + b4.x;
        o.y = (v[i].y - mu) * rs * g4.y + b4.y;
        o.z = (v[i].z - mu) * rs * g4.z + b4.z;
        o.w = (v[i].w - mu) * rs * g4.w + b4.w;
        o.x = o.x > 0.f ? o.x : 0.f;
        o.y = o.y > 0.f ? o.y : 0.f;
        o.z = o.z > 0.f ? o.z : 0.f;
        o.w = o.w > 0.f ? o.w : 0.f;
        *(float4*)&h[c] = o;
    }
}

// ---------------------------------------------------------------------------
// Running-mean over t (cumsum / (t+1)) + concat: Y[g,t, 0:L] = runmean,
// Y[g,t, L:2L] = M[g,t,:].  One thread per (group, channel); consecutive
// threads = consecutive channels -> coalesced at each t step.
// ---------------------------------------------------------------------------
__global__ __launch_bounds__(256) void cumsum_concat(
    const float* __restrict__ M, float* __restrict__ Y, int L)
{
    int idx = blockIdx.x * 256 + threadIdx.x;
    int g = idx / L, c = idx % L;
    if (g >= NGROUP) return;
    const float* mp = M + (size_t)g * 128 * L + c;
    float* yp = Y + (size_t)g * 128 * (2 * L) + c;
    float run = 0.f;
    for (int t = 0; t < 128; ++t) {
        float vv = mp[(size_t)t * L];
        run += vv;
        yp[(size_t)t * 2 * L]     = run / (float)(t + 1);
        yp[(size_t)t * 2 * L + L] = vv;
    }
}

// ---------------------------------------------------------------------------
static void run_layer(const float* X, int Lin, void* const* w,
                      float* Mb, float* Y, float* Hb, int chunk, hipStream_t s)
{
    const float* w1 = (const float*)w[0];
    const float* b1 = (const float*)w[1];
    const float* g  = (const float*)w[2];
    const float* bb = (const float*)w[3];
    const float* w2 = (const float*)w[4];
    const float* b2 = (const float*)w[5];

    for (int r0 = 0; r0 < R_TOTAL; r0 += chunk) {
        int rc = (R_TOTAL - r0) < chunk ? (R_TOTAL - r0) : chunk;
        // GEMM1: H[rc, HID] = X @ w1 + b1
        dim3 g1(HID / 128, rc / 128);
        hipLaunchKernelGGL((gemm_bias<128, 128, 16, 8, 8>), g1, dim3(256), 0, s,
                           X + (size_t)r0 * Lin, w1, b1, Hb, rc, HID, Lin);
        // LN + ReLU in-place
        hipLaunchKernelGGL(ln_relu, dim3(rc), dim3(256), 0, s, Hb, g, bb);
        // GEMM2: M[rc, Lin] = H @ w2 + b2
        if (Lin >= 512) {
            dim3 g2(Lin / 128, rc / 128);
            hipLaunchKernelGGL((gemm_bias<128, 128, 16, 8, 8>), g2, dim3(256), 0, s,
                               Hb, w2, b2, Mb + (size_t)r0 * Lin, rc, Lin, HID);
        } else {
            dim3 g2(Lin / 64, rc / 64);
            hipLaunchKernelGGL((gemm_bias<64, 64, 16, 4, 4>), g2, dim3(256), 0, s,
                               Hb, w2, b2, Mb + (size_t)r0 * Lin, rc, Lin, HID);
        }
    }
    int total = NGROUP * Lin;
    hipLaunchKernelGGL(cumsum_concat, dim3((total + 255) / 256), dim3(256), 0, s,
                       Mb, Y, Lin);
}

extern "C" void kernel_launch(void* const* d_in, const int* in_sizes, int n_in,
                              void* d_out, int out_size, void* d_ws, size_t ws_size,
                              hipStream_t stream)
{
    const float* x0 = (const float*)d_in[0];

    float* ws = (float*)d_ws;
    float* Y1 = ws;                                 // 12288 x 256
    float* Y2 = Y1 + (size_t)R_TOTAL * 256;         // 12288 x 512
    float* Mb = Y2 + (size_t)R_TOTAL * 512;         // 12288 x 512 (max)
    float* Hb = Mb + (size_t)R_TOTAL * 512;         // chunk x 8192

    size_t fixed_bytes = (size_t)R_TOTAL * (256 + 512 + 512) * 4;
    size_t avail = ws_size > fixed_bytes ? ws_size - fixed_bytes : 0;
    long chunk_l = (long)((avail / ((size_t)HID * 4)) / 128) * 128;
    int chunk = chunk_l > R_TOTAL ? R_TOTAL : (int)chunk_l;
    if (chunk < 128) chunk = 128;   // last-resort clamp

    run_layer(x0, 128, d_in + 1,  Mb, Y1,            Hb, chunk, stream);
    run_layer(Y1, 256, d_in + 7,  Mb, Y2,            Hb, chunk, stream);
    run_layer(Y2, 512, d_in + 13, Mb, (float*)d_out, Hb, chunk, stream);
}

// Round 4
// 2701.221 us; speedup vs baseline: 2.4842x; 2.4842x over previous
//
#include <hip/hip_runtime.h>
#include <hip/hip_bf16.h>
#include <stdint.h>

#define HID     8192
#define RTOT    12288    // 8*12*128 rows
#define NGRP    96       // (b,n) groups of 128 t-steps
#define EPS     1e-5f

typedef unsigned short u16;
typedef __attribute__((ext_vector_type(8))) __bf16 bf16x8;
typedef __attribute__((ext_vector_type(8))) short  short8;
typedef __attribute__((ext_vector_type(4))) float  f32x4;

// -----------------------------------------------------------------------------
// MFMA v_mfma_f32_16x16x32_bf16 fragment mapping (m162/m89-derived):
//   A: lane l holds A[row = l&15][k = 4*(l>>4) + (j&3) + 16*(j>>2)], j=0..7
//   B: lane l holds B[k = same kmap][col = l&15]
//   D: col = l&15, row = 4*(l>>4) + q   (m89-verified)
// Correctness note: A and B use the SAME lane->k bijection, so any consistent
// k-permutation cancels in the contraction; only the C/D mapping must be exact.
// Shuffled storage: one 512-elem "fragment line block" per (16-row x 32-k) tile:
//   block[l*8 + j].  A: [M/16][K/32][512], B: [K/32][N/16][512].
// -----------------------------------------------------------------------------
__device__ __forceinline__ int kmap(int l, int j) {
    return ((l >> 4) << 2) + (j & 3) + ((j >> 2) << 4);
}

__device__ __forceinline__ void split2(float x, u16& h, u16& lo) {
    __hip_bfloat16 bh = __float2bfloat16(x);
    float rem = x - __bfloat162float(bh);
    __hip_bfloat16 bl = __float2bfloat16(rem);
    h  = __builtin_bit_cast(u16, bh);
    lo = __builtin_bit_cast(u16, bl);
}

// ---------- fp32 [M][K] -> fragment-line shuffled hi/lo ----------------------
__global__ __launch_bounds__(256) void shuffle_a(
    const float* __restrict__ A, u16* __restrict__ Ahi, u16* __restrict__ Alo,
    int M16, int K)
{
    const int wid = blockIdx.x * 4 + (threadIdx.x >> 6);
    const int l   = threadIdx.x & 63;
    const int K32 = K >> 5;
    const int m16 = wid / K32, kt = wid % K32;
    if (m16 >= M16) return;
    const int r = (m16 << 4) + (l & 15);
    const float* ap = A + (size_t)r * K + (kt << 5);
    short8 vh, vl;
#pragma unroll
    for (int j = 0; j < 8; ++j) {
        u16 h, lo; split2(ap[kmap(l, j)], h, lo);
        vh[j] = (short)h; vl[j] = (short)lo;
    }
    const size_t off = ((size_t)(m16 * K32 + kt)) * 512 + l * 8;
    *(short8*)(Ahi + off) = vh;
    *(short8*)(Alo + off) = vl;
}

// ---------- fp32 [K][N] -> fragment-line shuffled hi/lo ----------------------
__global__ __launch_bounds__(256) void shuffle_b(
    const float* __restrict__ B, u16* __restrict__ Bhi, u16* __restrict__ Blo,
    int K32, int N)
{
    const int wid = blockIdx.x * 4 + (threadIdx.x >> 6);
    const int l   = threadIdx.x & 63;
    const int N16 = N >> 4;
    const int kt = wid / N16, nc = wid % N16;
    if (kt >= K32) return;
    const int n = (nc << 4) + (l & 15);
    short8 vh, vl;
#pragma unroll
    for (int j = 0; j < 8; ++j) {
        const int k = (kt << 5) + kmap(l, j);
        u16 h, lo; split2(B[(size_t)k * N + n], h, lo);
        vh[j] = (short)h; vl[j] = (short)lo;
    }
    const size_t off = ((size_t)(kt * N16 + nc)) * 512 + l * 8;
    *(short8*)(Bhi + off) = vh;
    *(short8*)(Blo + off) = vl;
}

// ---------- split-bf16 MFMA GEMM on shuffled operands ------------------------
// 256 thr = 4 waves; tile 128x128; wave (wr,wc) owns 64x64 = 4x4 16x16 frags.
// C = A@B (+bias) ; STATS: per-row sum/ssq atomics (for LN). ATOMC: atomicAdd C.
template<bool STATS, bool ATOMC>
__global__ __launch_bounds__(256) void gemm_shuf(
    const u16* __restrict__ Ahi, const u16* __restrict__ Alo,
    const u16* __restrict__ Bhi, const u16* __restrict__ Blo,
    const float* __restrict__ bias, float* __restrict__ C,
    float* __restrict__ ssum, float* __restrict__ sssq,
    int N, int K32, int ktn)
{
    __shared__ __align__(16) u16 As[2][8][512];
    __shared__ __align__(16) u16 Bs[2][8][512];

    const int tid = threadIdx.x;
    const int l   = tid & 63;
    const int wv  = tid >> 6;
    const int wr  = wv >> 1, wc = wv & 1;
    const int bm  = blockIdx.y, bn = blockIdx.x;
    const int N16 = N >> 4;
    const int kt0 = blockIdx.z * ktn;

    f32x4 acc[4][4];
#pragma unroll
    for (int m = 0; m < 4; ++m)
#pragma unroll
        for (int n = 0; n < 4; ++n) acc[m][n] = f32x4{0.f, 0.f, 0.f, 0.f};

    for (int t = 0; t < ktn; ++t) {
        const int kt = kt0 + t;
        // stage: 8 blocks x 64 lines x 16B per array -> 2 lines/thread
#pragma unroll
        for (int p = 0; p < 2; ++p) {
            const int idx = tid + p * 256;
            const int blk = idx >> 6, ln = idx & 63;
            const size_t ao = ((size_t)((bm * 8 + blk) * K32 + kt)) * 512 + ln * 8;
            const size_t bo = ((size_t)(kt * N16 + bn * 8 + blk)) * 512 + ln * 8;
            *(short8*)&As[0][blk][ln * 8] = *(const short8*)(Ahi + ao);
            *(short8*)&As[1][blk][ln * 8] = *(const short8*)(Alo + ao);
            *(short8*)&Bs[0][blk][ln * 8] = *(const short8*)(Bhi + bo);
            *(short8*)&Bs[1][blk][ln * 8] = *(const short8*)(Blo + bo);
        }
        __syncthreads();

        bf16x8 ah[4], al[4], bh[4], bl[4];
#pragma unroll
        for (int m = 0; m < 4; ++m) {
            ah[m] = *(const bf16x8*)&As[0][wr * 4 + m][l * 8];
            al[m] = *(const bf16x8*)&As[1][wr * 4 + m][l * 8];
        }
#pragma unroll
        for (int n = 0; n < 4; ++n) {
            bh[n] = *(const bf16x8*)&Bs[0][wc * 4 + n][l * 8];
            bl[n] = *(const bf16x8*)&Bs[1][wc * 4 + n][l * 8];
        }
#pragma unroll
        for (int m = 0; m < 4; ++m)
#pragma unroll
            for (int n = 0; n < 4; ++n) {
                acc[m][n] = __builtin_amdgcn_mfma_f32_16x16x32_bf16(ah[m], bh[n], acc[m][n], 0, 0, 0);
                acc[m][n] = __builtin_amdgcn_mfma_f32_16x16x32_bf16(al[m], bh[n], acc[m][n], 0, 0, 0);
                acc[m][n] = __builtin_amdgcn_mfma_f32_16x16x32_bf16(ah[m], bl[n], acc[m][n], 0, 0, 0);
            }
        __syncthreads();
    }

    // epilogue: D col = l&15, row = 4*(l>>4)+q
    const int c0 = bn * 128 + wc * 64 + (l & 15);
    const int r0 = bm * 128 + wr * 64 + ((l >> 4) << 2);
#pragma unroll
    for (int m = 0; m < 4; ++m)
#pragma unroll
        for (int n = 0; n < 4; ++n) {
            const int col = c0 + n * 16;
            const float bv = ATOMC ? 0.f : bias[col];
#pragma unroll
            for (int q = 0; q < 4; ++q) {
                const int row = r0 + m * 16 + q;
                const float v = acc[m][n][q] + bv;
                if (ATOMC) atomicAdd(&C[(size_t)row * N + col], v);
                else       C[(size_t)row * N + col] = v;
            }
        }
    if (STATS) {
#pragma unroll
        for (int m = 0; m < 4; ++m)
#pragma unroll
            for (int q = 0; q < 4; ++q) {
                float s = 0.f, s2 = 0.f;
#pragma unroll
                for (int n = 0; n < 4; ++n) {
                    const float v = acc[m][n][q] + bias[c0 + n * 16];
                    s += v; s2 += v * v;
                }
#pragma unroll
                for (int d = 1; d < 16; d <<= 1) {
                    s  += __shfl_xor(s, d, 64);
                    s2 += __shfl_xor(s2, d, 64);
                }
                if ((l & 15) == 0) {
                    const int row = r0 + m * 16 + q;
                    atomicAdd(&ssum[row], s);
                    atomicAdd(&sssq[row], s2);
                }
            }
    }
}

// ---------- LN + affine + ReLU + split + shuffle (H fp32 -> Hhi/Hlo) ---------
__global__ __launch_bounds__(256) void ln_shuf(
    const float* __restrict__ H, const float* __restrict__ ssum,
    const float* __restrict__ sssq, const float* __restrict__ g,
    const float* __restrict__ b, u16* __restrict__ Ohi, u16* __restrict__ Olo)
{
    const int wid = blockIdx.x * 4 + (threadIdx.x >> 6);
    const int l   = threadIdx.x & 63;
    const int m16 = wid >> 8, kt = wid & 255;   // K32 = 256 (HID)
    const int r = (m16 << 4) + (l & 15);
    const float sum = ssum[r], ssq = sssq[r];
    const float mu  = sum * (1.f / HID);
    float var = ssq * (1.f / HID) - mu * mu;
    var = var < 0.f ? 0.f : var;
    const float rs = rsqrtf(var + EPS);
    const float* hp = H + (size_t)r * HID + (kt << 5);
    short8 vh, vl;
#pragma unroll
    for (int j = 0; j < 8; ++j) {
        const int kk = kmap(l, j);
        const int k  = (kt << 5) + kk;
        float v = hp[kk];
        v = (v - mu) * rs * g[k] + b[k];
        v = v > 0.f ? v : 0.f;
        u16 h, lo; split2(v, h, lo);
        vh[j] = (short)h; vl[j] = (short)lo;
    }
    const size_t off = ((size_t)(m16 * 256 + kt)) * 512 + l * 8;
    *(short8*)(Ohi + off) = vh;
    *(short8*)(Olo + off) = vl;
}

// ---------- C init with bias (split-K atomic target) -------------------------
__global__ __launch_bounds__(256) void bias_init(
    float* __restrict__ C, const float* __restrict__ bias, int mask, int total)
{
    const int i = blockIdx.x * 256 + threadIdx.x;
    if (i < total) C[i] = bias[i & mask];
}

// ---------- running mean over t + concat -------------------------------------
__global__ __launch_bounds__(256) void cumsum_concat(
    const float* __restrict__ M, float* __restrict__ Y, int L)
{
    const int idx = blockIdx.x * 256 + threadIdx.x;
    const int g = idx / L, c = idx % L;
    if (g >= NGRP) return;
    const float* mp = M + (size_t)g * 128 * L + c;
    float* yp = Y + (size_t)g * 128 * (2 * L) + c;
    float run = 0.f;
    for (int t = 0; t < 128; ++t) {
        const float vv = mp[(size_t)t * L];
        run += vv;
        yp[(size_t)t * 2 * L]     = run / (float)(t + 1);
        yp[(size_t)t * 2 * L + L] = vv;
    }
}

// -----------------------------------------------------------------------------
extern "C" void kernel_launch(void* const* d_in, const int* in_sizes, int n_in,
                              void* d_out, int out_size, void* d_ws, size_t ws_size,
                              hipStream_t stream)
{
    const float* X0 = (const float*)d_in[0];

    // ---- pick row-chunk CH from actual ws_size (deterministic -> graph-safe)
    const size_t fixed =
        (size_t)RTOT * 256 * 4 +          // Y1
        (size_t)RTOT * 512 * 4 * 2 +      // Y2, C2
        (size_t)RTOT * 4 * 2 +            // ssum, sssq
        (size_t)RTOT * 512 * 2 * 2 +      // Ah, Al
        (size_t)512 * HID * 2 * 4 +       // B1h/l, B2h/l
        (size_t)64 * 1024;                // alignment slack
    int CH = 4096;
    while (CH > 512 && fixed + (size_t)CH * HID * 8 > ws_size) CH >>= 1;

    char* p = (char*)d_ws;
    auto carve = [&](size_t bytes) { char* r = p; p += (bytes + 255) & ~(size_t)255; return r; };
    float* H    = (float*)carve((size_t)CH * HID * 4);
    float* Y1   = (float*)carve((size_t)RTOT * 256 * 4);
    float* Y2   = (float*)carve((size_t)RTOT * 512 * 4);
    float* C2   = (float*)carve((size_t)RTOT * 512 * 4);
    float* ssum = (float*)carve((size_t)RTOT * 4);
    float* sssq = (float*)carve((size_t)RTOT * 4);
    u16*   Ah   = (u16*)carve((size_t)RTOT * 512 * 2);
    u16*   Al   = (u16*)carve((size_t)RTOT * 512 * 2);
    u16*   Hh   = (u16*)carve((size_t)CH * HID * 2);
    u16*   Hl   = (u16*)carve((size_t)CH * HID * 2);
    u16*   B1h  = (u16*)carve((size_t)512 * HID * 2);
    u16*   B1l  = (u16*)carve((size_t)512 * HID * 2);
    u16*   B2h  = (u16*)carve((size_t)512 * HID * 2);
    u16*   B2l  = (u16*)carve((size_t)512 * HID * 2);

    const float* Xsrc = X0;
    for (int layer = 0; layer < 3; ++layer) {
        const int Lin  = 128 << layer;
        const int K32i = Lin >> 5;
        const float* w1 = (const float*)d_in[1 + 6 * layer + 0];
        const float* b1 = (const float*)d_in[1 + 6 * layer + 1];
        const float* lg = (const float*)d_in[1 + 6 * layer + 2];
        const float* lb = (const float*)d_in[1 + 6 * layer + 3];
        const float* w2 = (const float*)d_in[1 + 6 * layer + 4];
        const float* b2 = (const float*)d_in[1 + 6 * layer + 5];

        {   // operand shuffles (small, one per layer)
            const int wa  = (RTOT / 16) * K32i;
            shuffle_a<<<dim3((wa + 3) / 4), dim3(256), 0, stream>>>(Xsrc, Ah, Al, RTOT / 16, Lin);
            const int wb1 = K32i * (HID / 16);
            shuffle_b<<<dim3((wb1 + 3) / 4), dim3(256), 0, stream>>>(w1, B1h, B1l, K32i, HID);
            const int wb2 = (HID / 32) * (Lin / 16);
            shuffle_b<<<dim3((wb2 + 3) / 4), dim3(256), 0, stream>>>(w2, B2h, B2l, HID / 32, Lin);
        }
        hipMemsetAsync(ssum, 0, RTOT * 4, stream);
        hipMemsetAsync(sssq, 0, RTOT * 4, stream);
        bias_init<<<dim3((RTOT * Lin) / 256), dim3(256), 0, stream>>>(C2, b2, Lin - 1, RTOT * Lin);

        // split-K factor: keep >=256 blocks in flight for GEMM2
        const int bmn = (Lin / 128) * (CH / 128);
        int z = 1;
        while (bmn * z < 256 && z < 16) z <<= 1;
        const int ktn2 = 256 / z;

        for (int ch = 0; ch < RTOT / CH; ++ch) {
            const u16* Ahc = Ah + (size_t)(ch * (CH / 16)) * K32i * 512;
            const u16* Alc = Al + (size_t)(ch * (CH / 16)) * K32i * 512;
            gemm_shuf<true, false><<<dim3(HID / 128, CH / 128, 1), dim3(256), 0, stream>>>(
                Ahc, Alc, B1h, B1l, b1, H, ssum + ch * CH, sssq + ch * CH, HID, K32i, K32i);
            ln_shuf<<<dim3((CH / 16) * 256 / 4), dim3(256), 0, stream>>>(
                H, ssum + ch * CH, sssq + ch * CH, lg, lb, Hh, Hl);
            gemm_shuf<false, true><<<dim3(Lin / 128, CH / 128, z), dim3(256), 0, stream>>>(
                Hh, Hl, B2h, B2l, b2, C2 + (size_t)ch * CH * Lin, nullptr, nullptr,
                Lin, HID / 32, ktn2);
        }
        float* Yout = (layer == 0) ? Y1 : (layer == 1 ? Y2 : (float*)d_out);
        cumsum_concat<<<dim3((NGRP * Lin + 255) / 256), dim3(256), 0, stream>>>(C2, Yout, Lin);
        Xsrc = Yout;
    }
}